// Round 1
// baseline (1536.249 us; speedup 1.0000x reference)
//
#include <hip/hip_runtime.h>

#define N_NODES 131072
#define MAXL 4096
#define NP 8

typedef __attribute__((ext_vector_type(8))) short bf16x8;
typedef __attribute__((ext_vector_type(4))) float f32x4;

// ws float offsets
#define OFF_QW     0u          // 64*256   folded (Q@WK)/16
#define OFF_QO     16384u      // 64*256   Q@WO^T
#define OFF_WF     32768u      // 256*256  WO@WV
#define OFF_QB     98304u      // 64
#define OFF_BVO    98368u      // 256
#define OFF_STARTS 98624u      // 65 ints (padded)
#define OFF_ASUM   98752u      // 64*64
#define OFF_Q      102848u     // 64*256
#define OFF_WQT    119232u     // 256*256
#define OFF_WOT    184768u     // 256*256
#define OFF_GP     250304u     // 8 * 64 * 16384  (end = 8638912 floats = 34.6 MB)

__device__ __forceinline__ unsigned short f2bf(float f) {
  union { float f; unsigned int u; } v; v.f = f;
  unsigned int u = v.u + 0x7FFFu + ((v.u >> 16) & 1u);  // RNE
  return (unsigned short)(u >> 16);
}

// cross-lane sum over kq = lane&7.
// xor1/xor2 via DPP quad_perm (VALU pipe), xor4 via ds_swizzle (LDS pipe).
__device__ __forceinline__ float xor1_add(float v) {
  int r = __builtin_amdgcn_update_dpp(0, __float_as_int(v), 0xB1, 0xF, 0xF, true); // [1,0,3,2]
  return v + __int_as_float(r);
}
__device__ __forceinline__ float xor2_add(float v) {
  int r = __builtin_amdgcn_update_dpp(0, __float_as_int(v), 0x4E, 0xF, 0xF, true); // [2,3,0,1]
  return v + __int_as_float(r);
}
__device__ __forceinline__ float xor4_add(float v) {
  int r = __builtin_amdgcn_ds_swizzle(__float_as_int(v), 0x101F);                  // xor lane^4
  return v + __int_as_float(r);
}
__device__ __forceinline__ float kq_sum(float v) { return xor4_add(xor2_add(xor1_add(v))); }

// ---------------- setup ----------------

// transpose WQ_w (z=0) and WO_w (z=1) into WQT / WOT
__global__ __launch_bounds__(256) void k_tr(const float* __restrict__ WQ_w,
    const float* __restrict__ WO_w, float* __restrict__ WQT, float* __restrict__ WOT)
{
  __shared__ float tile[32][33];
  const float* src = blockIdx.z ? WO_w : WQ_w;
  float* dst = blockIdx.z ? WOT : WQT;
  const int bx = blockIdx.x * 32, by = blockIdx.y * 32;
  const int tx = threadIdx.x & 31, ty = threadIdx.x >> 5;
  #pragma unroll
  for (int i = 0; i < 4; ++i)
    tile[ty + 8 * i][tx] = src[(size_t)(by + ty + 8 * i) * 256 + bx + tx];
  __syncthreads();
  #pragma unroll
  for (int i = 0; i < 4; ++i)
    dst[(size_t)(bx + ty + 8 * i) * 256 + by + tx] = tile[tx][ty + 8 * i];
}

// Q[c][d] = sum_k Qp[c][k] * WQT[k][d] + WQ_b[d]
__global__ __launch_bounds__(256) void k_q(const float* __restrict__ Qp,
    const float* __restrict__ WQT, const float* __restrict__ WQ_b,
    float* __restrict__ Q)
{
  const int c = blockIdx.x, d = threadIdx.x;
  float acc = WQ_b[d];
  for (int k = 0; k < 256; ++k)
    acc += Qp[c * 256 + k] * WQT[k * 256 + d];
  Q[c * 256 + d] = acc;
}

// QW = (Q@WK)/16 (exact, fp64 acc), QO = Q@WO^T, qb = (Q@WK_b)/16
__global__ __launch_bounds__(256) void k_fold(const float* __restrict__ Q,
    const float* __restrict__ WK_w, const float* __restrict__ WK_b,
    const float* __restrict__ WOT,
    float* __restrict__ QW, float* __restrict__ QO, float* __restrict__ qb)
{
  __shared__ float Qrow[256];
  const int c = blockIdx.x, d = threadIdx.x;
  Qrow[d] = Q[c * 256 + d];
  __syncthreads();
  double aqw = 0.0;
  float aqo = 0.f;
  for (int j = 0; j < 256; ++j) {
    float qcj = Qrow[j];
    aqw += (double)qcj * (double)WK_w[j * 256 + d];   // coalesced
    aqo += qcj * WOT[j * 256 + d];                    // coalesced
  }
  QW[c * 256 + d] = (float)(aqw * 0.0625);
  QO[c * 256 + d] = aqo;
  if (d == 0) {
    double s = 0.0;
    for (int j = 0; j < 256; ++j) s += (double)Qrow[j] * (double)WK_b[j];
    qb[c] = (float)(s * 0.0625);
  }
}

__global__ __launch_bounds__(256) void k_wf(const float* __restrict__ WO_w,
    const float* __restrict__ WV_w, const float* __restrict__ WV_b,
    float* __restrict__ Wf, float* __restrict__ bvo)
{
  const int i = blockIdx.x, d = threadIdx.x;
  float acc = 0.f;
  for (int j = 0; j < 256; ++j)
    acc += WO_w[i * 256 + j] * WV_w[j * 256 + d];
  Wf[i * 256 + d] = acc;
  if (d == 0) {
    float s = 0.f;
    for (int j = 0; j < 256; ++j) s += WV_b[j] * WO_w[i * 256 + j];
    bvo[i] = s;
  }
}

__global__ void k_starts(const int* __restrict__ batch, int* __restrict__ starts)
{
  int t = threadIdx.x;
  if (t > 64) return;
  if (t == 0) { starts[0] = 0; return; }
  if (t == 64) { starts[64] = N_NODES; return; }
  int lo = 0, hi = N_NODES;
  while (lo < hi) {
    int mid = (lo + hi) >> 1;
    if (batch[mid] < t) lo = mid + 1; else hi = mid;
  }
  starts[t] = lo;
}

// ---------------- fused: scores + softmax + argmax/mask + G (MFMA) ----------
// grid (NP, 64 graphs), 256 threads, chunk = 32 nodes.
// Score phase: lane = (cp = lane>>3, kq = lane&7). Thread owns TWO clusters
// (c0 = 16w+cp, c1 = c0+8) and k-slice [32kq, 32kq+32) of q held in REGISTERS
// (loaded once) -> each b128 xs read feeds 8 FMAs (2x the old ratio), no q
// staging, no qs bank conflicts. Partial-k sums reduced over kq with DPP
// (xor1/2 on VALU pipe) + ds_swizzle (xor4), written once to ss.
// xs columns XOR-swizzled (col ^ 4*((col>>5)&7)) so the 8-address-per-wave
// score reads are bank-conflict-free. 5 barriers/chunk (was 13).
// Stats/a-phase/MFMA G accumulation identical in math to previous version.

__global__ __launch_bounds__(256, 2) void k_fused(
    const float* __restrict__ x, const int* __restrict__ starts,
    const float* __restrict__ qw, const float* __restrict__ qbv,
    float* __restrict__ Gp, float* __restrict__ asum,
    float* __restrict__ out_arg, float* __restrict__ out_msk)
{
  __shared__ float xs[32][256];                        // fp32 chunk, col-swizzled
  __shared__ float ss[32][68];                         // scores [n][c], 16B-aligned rows
  __shared__ float stats_m[32], stats_i[32];
  __shared__ __align__(16) unsigned short As[64][40];  // a bf16 [c][n]
  __shared__ __align__(16) unsigned short XsT[256][40];// x bf16 transposed [d][n]

  const int t = threadIdx.x;
  const int p = blockIdx.x, b = blockIdx.y;
  const int s0 = starts[b], s1 = starts[b + 1];
  const int w = t >> 6, lane = t & 63;
  const int cp = lane >> 3, kq = lane & 7;
  const int c0 = w * 16 + cp, c1 = c0 + 8;

  // q slices in registers: 2 clusters x 32 k = 16 float4 (one-time global read)
  float4 q0[8], q1[8];
  #pragma unroll
  for (int j = 0; j < 8; ++j) {
    q0[j] = *(const float4*)&qw[(size_t)c0 * 256 + kq * 32 + j * 4];
    q1[j] = *(const float4*)&qw[(size_t)c1 * 256 + kq * 32 + j * 4];
  }
  const float qb0 = qbv[c0], qb1 = qbv[c1];

  f32x4 gacc[16];
  #pragma unroll
  for (int i = 0; i < 16; ++i) gacc[i] = (f32x4){0.f, 0.f, 0.f, 0.f};
  float asv0 = 0.f, asv1 = 0.f;

  const int stcol = (lane * 4) ^ (4 * ((lane >> 3) & 7));  // staging store column
  const int dsz   = t ^ (4 * ((t >> 5) & 7));              // XsT-fill read column
  const int swz   = 4 * kq;                                // score read column xor

  #pragma unroll 1
  for (int base = s0 + p * 32; base < s1; base += NP * 32) {
    // ---- stage x chunk (coalesced global read, swizzled LDS store)
    #pragma unroll
    for (int i = 0; i < 8; ++i) {
      int r = w * 8 + i;
      int gr = base + r; if (gr >= s1) gr = s1 - 1;
      float4 v = *(const float4*)&x[(size_t)gr * 256 + lane * 4];
      *(float4*)&xs[r][stcol] = v;
    }
    __syncthreads();
    // ---- XsT fill: thread d=t packs its column as bf16 [d][n]
    #pragma unroll
    for (int g = 0; g < 8; ++g) {
      ushort4 pk;
      pk.x = f2bf(xs[g * 4 + 0][dsz]);
      pk.y = f2bf(xs[g * 4 + 1][dsz]);
      pk.z = f2bf(xs[g * 4 + 2][dsz]);
      pk.w = f2bf(xs[g * 4 + 3][dsz]);
      *(ushort4*)&XsT[t][g * 4] = pk;
    }
    // ---- scores: 2 halves x 16 nodes, q from regs, exact fp32
    #pragma unroll 1
    for (int h = 0; h < 2; ++h) {
      float a0[16], a1[16];
      #pragma unroll
      for (int n = 0; n < 16; ++n) { a0[n] = 0.f; a1[n] = 0.f; }
      const float* xb = &xs[h * 16][0];
      #pragma unroll
      for (int k4 = 0; k4 < 8; ++k4) {
        const float4 qa = q0[k4], qc = q1[k4];
        const int col = kq * 32 + ((k4 * 4) ^ swz);   // swizzled addr of orig col kq*32+k4*4
        #pragma unroll
        for (int n = 0; n < 16; ++n) {
          float4 xv = *(const float4*)&xb[n * 256 + col];
          a0[n] = fmaf(qa.w, xv.w, fmaf(qa.z, xv.z, fmaf(qa.y, xv.y, fmaf(qa.x, xv.x, a0[n]))));
          a1[n] = fmaf(qc.w, xv.w, fmaf(qc.z, xv.z, fmaf(qc.y, xv.y, fmaf(qc.x, xv.x, a1[n]))));
        }
      }
      // reduce partial k-sums over kq; lane kq writes nodes {2kq, 2kq+1}
      #pragma unroll
      for (int n = 0; n < 16; ++n) {
        float s0v = kq_sum(a0[n]);
        float s1v = kq_sum(a1[n]);
        if (kq == (n >> 1)) {
          ss[h * 16 + n][c0] = s0v + qb0;
          ss[h * 16 + n][c1] = s1v + qb1;
        }
      }
    }
    __syncthreads();
    // ---- softmax stats + argmax: 8 threads/node (oct split + shfl reduce)
    {
      const int nn = t >> 3, oct = t & 7;
      float v8[8];
      #pragma unroll
      for (int u = 0; u < 8; ++u) v8[u] = ss[nn][oct * 8 + u];
      float m = v8[0]; int am = oct * 8;
      #pragma unroll
      for (int u = 1; u < 8; ++u)
        if (v8[u] > m) { m = v8[u]; am = oct * 8 + u; }   // strict >: first max
      #pragma unroll
      for (int d = 1; d < 8; d <<= 1) {
        float mo = __shfl_xor(m, d);
        int ao = __shfl_xor(am, d);
        if (mo > m || (mo == m && ao < am)) { m = mo; am = ao; }
      }
      float s = 0.f;
      #pragma unroll
      for (int u = 0; u < 8; ++u) s += __expf(v8[u] - m);
      #pragma unroll
      for (int d = 1; d < 8; d <<= 1) s += __shfl_xor(s, d);
      if (oct == 0) {
        stats_m[nn] = m;
        stats_i[nn] = 1.f / s;
        int n = base + nn;
        if (n < s1) {
          int pos = n - s0;
          out_arg[(size_t)b * MAXL + pos] = (float)am;
          out_msk[(size_t)b * MAXL + pos] = 1.0f;
        }
      }
    }
    __syncthreads();
    // ---- a-values -> As (bf16) + asum; thread covers n in [4kq, 4kq+4) for c0,c1
    {
      unsigned short pb0[4], pb1[4];
      #pragma unroll
      for (int i = 0; i < 4; ++i) {
        int nn = 4 * kq + i;
        bool valid = (base + nn) < s1;
        float m = stats_m[nn], inv = stats_i[nn];
        float av0 = valid ? __expf(ss[nn][c0] - m) * inv : 0.f;
        float av1 = valid ? __expf(ss[nn][c1] - m) * inv : 0.f;
        asv0 += av0; asv1 += av1;
        pb0[i] = f2bf(av0);
        pb1[i] = f2bf(av1);
      }
      *(ushort4*)&As[c0][4 * kq] = *(const ushort4*)pb0;
      *(ushort4*)&As[c1][4 * kq] = *(const ushort4*)pb1;
    }
    __syncthreads();
    // ---- G MFMA: wave w owns clusters 16w..16w+16
    {
      const int q = lane >> 4, mm = lane & 15;
      bf16x8 afrag = *(const bf16x8*)&As[16 * w + mm][q * 8];
      #pragma unroll
      for (int dt = 0; dt < 16; ++dt) {
        bf16x8 bfrag = *(const bf16x8*)&XsT[16 * dt + mm][q * 8];
        gacc[dt] = __builtin_amdgcn_mfma_f32_16x16x32_bf16(afrag, bfrag, gacc[dt], 0, 0, 0);
      }
    }
    __syncthreads();
  }

  // ---- epilogue: store G slab (D layout: row=4*(lane>>4)+r, col=lane&15)
  {
    float* g = Gp + ((size_t)p * 64 + b) * 16384;
    const int q = lane >> 4, mm = lane & 15;
    #pragma unroll
    for (int dt = 0; dt < 16; ++dt)
      #pragma unroll
      for (int r = 0; r < 4; ++r)
        g[(size_t)(16 * w + q * 4 + r) * 256 + 16 * dt + mm] = gacc[dt][r];
  }
  // asum: reduce per-thread partials over kq, one atomic per cluster
  asv0 = kq_sum(asv0);
  asv1 = kq_sum(asv1);
  if (kq == 0) {
    atomicAdd(&asum[b * 64 + c0], asv0);
    atomicAdd(&asum[b * 64 + c1], asv1);
  }
}

// ---------------- finalize: out = relu(qo + (sum_p Gp)@Wf^T + asum*bvo + b) --

__global__ __launch_bounds__(256) void k_final(const float* __restrict__ Gp,
    int npart, const float* __restrict__ Wf, const float* __restrict__ qo,
    const float* __restrict__ asum, const float* __restrict__ bvo,
    const float* __restrict__ WO_b, float* __restrict__ out)
{
  __shared__ float gs[64 * 68];
  __shared__ float wfs[64 * 68];
  const int t = threadIdx.x;
  const int b = blockIdx.x >> 2;
  const int is = (blockIdx.x & 3) * 64;
  const int tx = t & 15, ty = t >> 4;
  const int sr = t >> 4, sq = t & 15;

  float acc[4][4];
  #pragma unroll
  for (int j = 0; j < 4; ++j)
    #pragma unroll
    for (int u = 0; u < 4; ++u) acc[j][u] = 0.f;

  for (int kc = 0; kc < 4; ++kc) {
    const int k0 = kc * 64;
    #pragma unroll
    for (int u = 0; u < 4; ++u) {
      int row = sr + 16 * u;
      float4 g = make_float4(0.f, 0.f, 0.f, 0.f);
      for (int p = 0; p < npart; ++p) {
        float4 gv = *(const float4*)&Gp[((size_t)p * 64 + b) * 16384
                                        + row * 256 + k0 + sq * 4];
        g.x += gv.x; g.y += gv.y; g.z += gv.z; g.w += gv.w;
      }
      *(float4*)&gs[row * 68 + sq * 4] = g;
      *(float4*)&wfs[row * 68 + sq * 4] =
          *(const float4*)&Wf[(size_t)(is + row) * 256 + k0 + sq * 4];
    }
    __syncthreads();
    #pragma unroll
    for (int k4 = 0; k4 < 16; ++k4) {
      float4 gr[4], wr[4];
      #pragma unroll
      for (int j = 0; j < 4; ++j) gr[j] = *(const float4*)&gs[(ty + 16 * j) * 68 + k4 * 4];
      #pragma unroll
      for (int u = 0; u < 4; ++u) wr[u] = *(const float4*)&wfs[(tx + 16 * u) * 68 + k4 * 4];
      #pragma unroll
      for (int j = 0; j < 4; ++j)
        #pragma unroll
        for (int u = 0; u < 4; ++u)
          acc[j][u] += gr[j].x * wr[u].x + gr[j].y * wr[u].y
                     + gr[j].z * wr[u].z + gr[j].w * wr[u].w;
    }
    __syncthreads();
  }

  #pragma unroll
  for (int j = 0; j < 4; ++j)
    #pragma unroll
    for (int u = 0; u < 4; ++u) {
      int cc = ty + 16 * j, i = is + tx + 16 * u;
      float v = acc[j][u] + qo[cc * 256 + i] + asum[b * 64 + cc] * bvo[i] + WO_b[i];
      out[(size_t)b * 16384 + cc * 256 + i] = fmaxf(v, 0.f);
    }
}

// ---------------- launch ----------------

extern "C" void kernel_launch(void* const* d_in, const int* in_sizes, int n_in,
                              void* d_out, int out_size, void* d_ws, size_t ws_size,
                              hipStream_t stream) {
  const float* x    = (const float*)d_in[0];
  const int*   batch= (const int*)d_in[1];
  const float* Qp   = (const float*)d_in[2];
  const float* WQ_w = (const float*)d_in[3];
  const float* WQ_b = (const float*)d_in[4];
  const float* WK_w = (const float*)d_in[5];
  const float* WK_b = (const float*)d_in[6];
  const float* WV_w = (const float*)d_in[7];
  const float* WV_b = (const float*)d_in[8];
  const float* WO_w = (const float*)d_in[9];
  const float* WO_b = (const float*)d_in[10];

  float* ws   = (float*)d_ws;
  float* QW   = ws + OFF_QW;
  float* QO   = ws + OFF_QO;
  float* Wf   = ws + OFF_WF;
  float* qb   = ws + OFF_QB;
  float* bvo  = ws + OFF_BVO;
  int*   starts = (int*)(ws + OFF_STARTS);
  float* asum = ws + OFF_ASUM;
  float* Q    = ws + OFF_Q;
  float* WQT  = ws + OFF_WQT;
  float* WOT  = ws + OFF_WOT;
  float* Gp   = ws + OFF_GP;

  float* out     = (float*)d_out;                 // [64][64][256]
  float* out_arg = out + 64 * 64 * 256;           // [64][4096]
  float* out_msk = out_arg + 64 * MAXL;           // [64][4096]

  hipMemsetAsync(asum, 0, 64 * 64 * sizeof(float), stream);
  hipMemsetAsync(out_arg, 0, (size_t)2 * 64 * MAXL * sizeof(float), stream);

  k_tr<<<dim3(8, 8, 2), 256, 0, stream>>>(WQ_w, WO_w, WQT, WOT);
  k_wf<<<256, 256, 0, stream>>>(WO_w, WV_w, WV_b, Wf, bvo);
  k_starts<<<1, 128, 0, stream>>>(batch, starts);
  k_q<<<64, 256, 0, stream>>>(Qp, WQT, WQ_b, Q);
  k_fold<<<64, 256, 0, stream>>>(Q, WK_w, WK_b, WOT, QW, QO, qb);

  k_fused<<<dim3(NP, 64), 256, 0, stream>>>(x, starts, QW, qb, Gp, asum,
                                            out_arg, out_msk);
  k_final<<<64 * 4, 256, 0, stream>>>(Gp, NP, Wf, QO, asum, bvo, WO_b, out);
}

// Round 2
// 725.367 us; speedup vs baseline: 2.1179x; 2.1179x over previous
//
#include <hip/hip_runtime.h>

#define N_NODES 131072
#define MAXL 4096
#define NP 8

typedef __attribute__((ext_vector_type(8))) short bf16x8;
typedef __attribute__((ext_vector_type(4))) float f32x4;

// ws float offsets
#define OFF_QW     0u          // 64*256   folded (Q@WK)/16
#define OFF_QO     16384u      // 64*256   Q@WO^T
#define OFF_WF     32768u      // 256*256  WO@WV
#define OFF_QB     98304u      // 64
#define OFF_BVO    98368u      // 256
#define OFF_STARTS 98624u      // 65 ints (padded)
#define OFF_ASUM   98752u      // 64*64
#define OFF_Q      102848u     // 64*256
#define OFF_WQT    119232u     // 256*256
#define OFF_WOT    184768u     // 256*256
#define OFF_GP     250304u     // 8 * 64 * 16384  (end = 8638912 floats = 34.6 MB)

__device__ __forceinline__ unsigned short f2bf(float f) {
  union { float f; unsigned int u; } v; v.f = f;
  unsigned int u = v.u + 0x7FFFu + ((v.u >> 16) & 1u);  // RNE
  return (unsigned short)(u >> 16);
}

// cross-lane sum over kq = lane&7.
// xor1/xor2 via DPP quad_perm (VALU pipe), xor4 via ds_swizzle (LDS pipe).
__device__ __forceinline__ float xor1_add(float v) {
  int r = __builtin_amdgcn_update_dpp(0, __float_as_int(v), 0xB1, 0xF, 0xF, true); // [1,0,3,2]
  return v + __int_as_float(r);
}
__device__ __forceinline__ float xor2_add(float v) {
  int r = __builtin_amdgcn_update_dpp(0, __float_as_int(v), 0x4E, 0xF, 0xF, true); // [2,3,0,1]
  return v + __int_as_float(r);
}
__device__ __forceinline__ float xor4_add(float v) {
  int r = __builtin_amdgcn_ds_swizzle(__float_as_int(v), 0x101F);                  // xor lane^4
  return v + __int_as_float(r);
}
__device__ __forceinline__ float kq_sum(float v) { return xor4_add(xor2_add(xor1_add(v))); }

// ---------------- setup ----------------

// transpose WQ_w (z=0) and WO_w (z=1) into WQT / WOT
__global__ __launch_bounds__(256) void k_tr(const float* __restrict__ WQ_w,
    const float* __restrict__ WO_w, float* __restrict__ WQT, float* __restrict__ WOT)
{
  __shared__ float tile[32][33];
  const float* src = blockIdx.z ? WO_w : WQ_w;
  float* dst = blockIdx.z ? WOT : WQT;
  const int bx = blockIdx.x * 32, by = blockIdx.y * 32;
  const int tx = threadIdx.x & 31, ty = threadIdx.x >> 5;
  #pragma unroll
  for (int i = 0; i < 4; ++i)
    tile[ty + 8 * i][tx] = src[(size_t)(by + ty + 8 * i) * 256 + bx + tx];
  __syncthreads();
  #pragma unroll
  for (int i = 0; i < 4; ++i)
    dst[(size_t)(bx + ty + 8 * i) * 256 + by + tx] = tile[tx][ty + 8 * i];
}

// Q[c][d] = sum_k Qp[c][k] * WQT[k][d] + WQ_b[d]
__global__ __launch_bounds__(256) void k_q(const float* __restrict__ Qp,
    const float* __restrict__ WQT, const float* __restrict__ WQ_b,
    float* __restrict__ Q)
{
  const int c = blockIdx.x, d = threadIdx.x;
  float acc = WQ_b[d];
  for (int k = 0; k < 256; ++k)
    acc += Qp[c * 256 + k] * WQT[k * 256 + d];
  Q[c * 256 + d] = acc;
}

// QW = (Q@WK)/16 (exact, fp64 acc), QO = Q@WO^T, qb = (Q@WK_b)/16
__global__ __launch_bounds__(256) void k_fold(const float* __restrict__ Q,
    const float* __restrict__ WK_w, const float* __restrict__ WK_b,
    const float* __restrict__ WOT,
    float* __restrict__ QW, float* __restrict__ QO, float* __restrict__ qb)
{
  __shared__ float Qrow[256];
  const int c = blockIdx.x, d = threadIdx.x;
  Qrow[d] = Q[c * 256 + d];
  __syncthreads();
  double aqw = 0.0;
  float aqo = 0.f;
  for (int j = 0; j < 256; ++j) {
    float qcj = Qrow[j];
    aqw += (double)qcj * (double)WK_w[j * 256 + d];   // coalesced
    aqo += qcj * WOT[j * 256 + d];                    // coalesced
  }
  QW[c * 256 + d] = (float)(aqw * 0.0625);
  QO[c * 256 + d] = aqo;
  if (d == 0) {
    double s = 0.0;
    for (int j = 0; j < 256; ++j) s += (double)Qrow[j] * (double)WK_b[j];
    qb[c] = (float)(s * 0.0625);
  }
}

__global__ __launch_bounds__(256) void k_wf(const float* __restrict__ WO_w,
    const float* __restrict__ WV_w, const float* __restrict__ WV_b,
    float* __restrict__ Wf, float* __restrict__ bvo)
{
  const int i = blockIdx.x, d = threadIdx.x;
  float acc = 0.f;
  for (int j = 0; j < 256; ++j)
    acc += WO_w[i * 256 + j] * WV_w[j * 256 + d];
  Wf[i * 256 + d] = acc;
  if (d == 0) {
    float s = 0.f;
    for (int j = 0; j < 256; ++j) s += WV_b[j] * WO_w[i * 256 + j];
    bvo[i] = s;
  }
}

__global__ void k_starts(const int* __restrict__ batch, int* __restrict__ starts)
{
  int t = threadIdx.x;
  if (t > 64) return;
  if (t == 0) { starts[0] = 0; return; }
  if (t == 64) { starts[64] = N_NODES; return; }
  int lo = 0, hi = N_NODES;
  while (lo < hi) {
    int mid = (lo + hi) >> 1;
    if (batch[mid] < t) lo = mid + 1; else hi = mid;
  }
  starts[t] = lo;
}

// ---------------- fused: scores + softmax + argmax/mask + G (MFMA) ----------
// grid (NP, 64 graphs), 256 threads, chunk = 32 nodes.
// Score phase: lane = (cp = lane>>3, kq = lane&7). Thread owns TWO clusters
// (c0 = 16w+cp, c1 = c0+8) and k-slice [32kq, 32kq+32) of q held in REGISTERS.
// Nodes processed in blocks of 8 (a0[8]+a1[8] = 16 live accumulators) so the
// whole score state stays in VGPRs -- round 1's 16-node blocks (32 accums)
// demoted to scratch (VGPR_Count=128, 2.8 GB scratch writes, 5.7x regression).
// Each b128 xs read feeds 8 FMAs; partial-k sums reduced over kq with DPP
// (xor1/2) + ds_swizzle (xor4). xs columns XOR-swizzled so score reads are
// bank-conflict-free. 5 barriers/chunk.

__global__ __launch_bounds__(256, 2) void k_fused(
    const float* __restrict__ x, const int* __restrict__ starts,
    const float* __restrict__ qw, const float* __restrict__ qbv,
    float* __restrict__ Gp, float* __restrict__ asum,
    float* __restrict__ out_arg, float* __restrict__ out_msk)
{
  __shared__ float xs[32][256];                        // fp32 chunk, col-swizzled
  __shared__ float ss[32][68];                         // scores [n][c], 16B-aligned rows
  __shared__ float stats_m[32], stats_i[32];
  __shared__ __align__(16) unsigned short As[64][40];  // a bf16 [c][n]
  __shared__ __align__(16) unsigned short XsT[256][40];// x bf16 transposed [d][n]

  const int t = threadIdx.x;
  const int p = blockIdx.x, b = blockIdx.y;
  const int s0 = starts[b], s1 = starts[b + 1];
  const int w = t >> 6, lane = t & 63;
  const int cp = lane >> 3, kq = lane & 7;
  const int c0 = w * 16 + cp, c1 = c0 + 8;

  // q slices in registers: 2 clusters x 32 k = 16 float4 (one-time global read)
  float4 q0[8], q1[8];
  #pragma unroll
  for (int j = 0; j < 8; ++j) {
    q0[j] = *(const float4*)&qw[(size_t)c0 * 256 + kq * 32 + j * 4];
    q1[j] = *(const float4*)&qw[(size_t)c1 * 256 + kq * 32 + j * 4];
  }
  const float qb0 = qbv[c0], qb1 = qbv[c1];

  f32x4 gacc[16];
  #pragma unroll
  for (int i = 0; i < 16; ++i) gacc[i] = (f32x4){0.f, 0.f, 0.f, 0.f};
  float asv0 = 0.f, asv1 = 0.f;

  const int stcol = (lane * 4) ^ (4 * ((lane >> 3) & 7));  // staging store column
  const int dsz   = t ^ (4 * ((t >> 5) & 7));              // XsT-fill read column
  const int swz   = 4 * kq;                                // score read column xor

  #pragma unroll 1
  for (int base = s0 + p * 32; base < s1; base += NP * 32) {
    // ---- stage x chunk (coalesced global read, swizzled LDS store)
    #pragma unroll
    for (int i = 0; i < 8; ++i) {
      int r = w * 8 + i;
      int gr = base + r; if (gr >= s1) gr = s1 - 1;
      float4 v = *(const float4*)&x[(size_t)gr * 256 + lane * 4];
      *(float4*)&xs[r][stcol] = v;
    }
    __syncthreads();
    // ---- XsT fill: thread d=t packs its column as bf16 [d][n]
    #pragma unroll
    for (int g = 0; g < 8; ++g) {
      ushort4 pk;
      pk.x = f2bf(xs[g * 4 + 0][dsz]);
      pk.y = f2bf(xs[g * 4 + 1][dsz]);
      pk.z = f2bf(xs[g * 4 + 2][dsz]);
      pk.w = f2bf(xs[g * 4 + 3][dsz]);
      *(ushort4*)&XsT[t][g * 4] = pk;
    }
    // ---- scores: 4 blocks x 8 nodes, q from regs, exact fp32
    #pragma unroll 1
    for (int h = 0; h < 4; ++h) {
      float a0[8], a1[8];
      #pragma unroll
      for (int n = 0; n < 8; ++n) { a0[n] = 0.f; a1[n] = 0.f; }
      const float* xb = &xs[h * 8][0];
      #pragma unroll
      for (int k4 = 0; k4 < 8; ++k4) {
        const float4 qa = q0[k4], qc = q1[k4];
        const int col = kq * 32 + ((k4 * 4) ^ swz);   // swizzled addr of orig col kq*32+k4*4
        #pragma unroll
        for (int n = 0; n < 8; ++n) {
          float4 xv = *(const float4*)&xb[n * 256 + col];
          a0[n] = fmaf(qa.w, xv.w, fmaf(qa.z, xv.z, fmaf(qa.y, xv.y, fmaf(qa.x, xv.x, a0[n]))));
          a1[n] = fmaf(qc.w, xv.w, fmaf(qc.z, xv.z, fmaf(qc.y, xv.y, fmaf(qc.x, xv.x, a1[n]))));
        }
      }
      // reduce partial k-sums over kq; lane kq writes node h*8+kq
      #pragma unroll
      for (int n = 0; n < 8; ++n) {
        float s0v = kq_sum(a0[n]);
        float s1v = kq_sum(a1[n]);
        if (kq == n) {
          ss[h * 8 + n][c0] = s0v + qb0;
          ss[h * 8 + n][c1] = s1v + qb1;
        }
      }
    }
    __syncthreads();
    // ---- softmax stats + argmax: 8 threads/node (oct split + shfl reduce)
    {
      const int nn = t >> 3, oct = t & 7;
      float v8[8];
      #pragma unroll
      for (int u = 0; u < 8; ++u) v8[u] = ss[nn][oct * 8 + u];
      float m = v8[0]; int am = oct * 8;
      #pragma unroll
      for (int u = 1; u < 8; ++u)
        if (v8[u] > m) { m = v8[u]; am = oct * 8 + u; }   // strict >: first max
      #pragma unroll
      for (int d = 1; d < 8; d <<= 1) {
        float mo = __shfl_xor(m, d);
        int ao = __shfl_xor(am, d);
        if (mo > m || (mo == m && ao < am)) { m = mo; am = ao; }
      }
      float s = 0.f;
      #pragma unroll
      for (int u = 0; u < 8; ++u) s += __expf(v8[u] - m);
      #pragma unroll
      for (int d = 1; d < 8; d <<= 1) s += __shfl_xor(s, d);
      if (oct == 0) {
        stats_m[nn] = m;
        stats_i[nn] = 1.f / s;
        int n = base + nn;
        if (n < s1) {
          int pos = n - s0;
          out_arg[(size_t)b * MAXL + pos] = (float)am;
          out_msk[(size_t)b * MAXL + pos] = 1.0f;
        }
      }
    }
    __syncthreads();
    // ---- a-values -> As (bf16) + asum; thread covers n in [4kq, 4kq+4) for c0,c1
    {
      unsigned short pb0[4], pb1[4];
      #pragma unroll
      for (int i = 0; i < 4; ++i) {
        int nn = 4 * kq + i;
        bool valid = (base + nn) < s1;
        float m = stats_m[nn], inv = stats_i[nn];
        float av0 = valid ? __expf(ss[nn][c0] - m) * inv : 0.f;
        float av1 = valid ? __expf(ss[nn][c1] - m) * inv : 0.f;
        asv0 += av0; asv1 += av1;
        pb0[i] = f2bf(av0);
        pb1[i] = f2bf(av1);
      }
      *(ushort4*)&As[c0][4 * kq] = *(const ushort4*)pb0;
      *(ushort4*)&As[c1][4 * kq] = *(const ushort4*)pb1;
    }
    __syncthreads();
    // ---- G MFMA: wave w owns clusters 16w..16w+16
    {
      const int q = lane >> 4, mm = lane & 15;
      bf16x8 afrag = *(const bf16x8*)&As[16 * w + mm][q * 8];
      #pragma unroll
      for (int dt = 0; dt < 16; ++dt) {
        bf16x8 bfrag = *(const bf16x8*)&XsT[16 * dt + mm][q * 8];
        gacc[dt] = __builtin_amdgcn_mfma_f32_16x16x32_bf16(afrag, bfrag, gacc[dt], 0, 0, 0);
      }
    }
    __syncthreads();
  }

  // ---- epilogue: store G slab (D layout: row=4*(lane>>4)+r, col=lane&15)
  {
    float* g = Gp + ((size_t)p * 64 + b) * 16384;
    const int q = lane >> 4, mm = lane & 15;
    #pragma unroll
    for (int dt = 0; dt < 16; ++dt)
      #pragma unroll
      for (int r = 0; r < 4; ++r)
        g[(size_t)(16 * w + q * 4 + r) * 256 + 16 * dt + mm] = gacc[dt][r];
  }
  // asum: reduce per-thread partials over kq, one atomic per cluster
  asv0 = kq_sum(asv0);
  asv1 = kq_sum(asv1);
  if (kq == 0) {
    atomicAdd(&asum[b * 64 + c0], asv0);
    atomicAdd(&asum[b * 64 + c1], asv1);
  }
}

// ---------------- finalize: out = relu(qo + (sum_p Gp)@Wf^T + asum*bvo + b) --

__global__ __launch_bounds__(256) void k_final(const float* __restrict__ Gp,
    int npart, const float* __restrict__ Wf, const float* __restrict__ qo,
    const float* __restrict__ asum, const float* __restrict__ bvo,
    const float* __restrict__ WO_b, float* __restrict__ out)
{
  __shared__ float gs[64 * 68];
  __shared__ float wfs[64 * 68];
  const int t = threadIdx.x;
  const int b = blockIdx.x >> 2;
  const int is = (blockIdx.x & 3) * 64;
  const int tx = t & 15, ty = t >> 4;
  const int sr = t >> 4, sq = t & 15;

  float acc[4][4];
  #pragma unroll
  for (int j = 0; j < 4; ++j)
    #pragma unroll
    for (int u = 0; u < 4; ++u) acc[j][u] = 0.f;

  for (int kc = 0; kc < 4; ++kc) {
    const int k0 = kc * 64;
    #pragma unroll
    for (int u = 0; u < 4; ++u) {
      int row = sr + 16 * u;
      float4 g = make_float4(0.f, 0.f, 0.f, 0.f);
      for (int p = 0; p < npart; ++p) {
        float4 gv = *(const float4*)&Gp[((size_t)p * 64 + b) * 16384
                                        + row * 256 + k0 + sq * 4];
        g.x += gv.x; g.y += gv.y; g.z += gv.z; g.w += gv.w;
      }
      *(float4*)&gs[row * 68 + sq * 4] = g;
      *(float4*)&wfs[row * 68 + sq * 4] =
          *(const float4*)&Wf[(size_t)(is + row) * 256 + k0 + sq * 4];
    }
    __syncthreads();
    #pragma unroll
    for (int k4 = 0; k4 < 16; ++k4) {
      float4 gr[4], wr[4];
      #pragma unroll
      for (int j = 0; j < 4; ++j) gr[j] = *(const float4*)&gs[(ty + 16 * j) * 68 + k4 * 4];
      #pragma unroll
      for (int u = 0; u < 4; ++u) wr[u] = *(const float4*)&wfs[(tx + 16 * u) * 68 + k4 * 4];
      #pragma unroll
      for (int j = 0; j < 4; ++j)
        #pragma unroll
        for (int u = 0; u < 4; ++u)
          acc[j][u] += gr[j].x * wr[u].x + gr[j].y * wr[u].y
                     + gr[j].z * wr[u].z + gr[j].w * wr[u].w;
    }
    __syncthreads();
  }

  #pragma unroll
  for (int j = 0; j < 4; ++j)
    #pragma unroll
    for (int u = 0; u < 4; ++u) {
      int cc = ty + 16 * j, i = is + tx + 16 * u;
      float v = acc[j][u] + qo[cc * 256 + i] + asum[b * 64 + cc] * bvo[i] + WO_b[i];
      out[(size_t)b * 16384 + cc * 256 + i] = fmaxf(v, 0.f);
    }
}

// ---------------- launch ----------------

extern "C" void kernel_launch(void* const* d_in, const int* in_sizes, int n_in,
                              void* d_out, int out_size, void* d_ws, size_t ws_size,
                              hipStream_t stream) {
  const float* x    = (const float*)d_in[0];
  const int*   batch= (const int*)d_in[1];
  const float* Qp   = (const float*)d_in[2];
  const float* WQ_w = (const float*)d_in[3];
  const float* WQ_b = (const float*)d_in[4];
  const float* WK_w = (const float*)d_in[5];
  const float* WK_b = (const float*)d_in[6];
  const float* WV_w = (const float*)d_in[7];
  const float* WV_b = (const float*)d_in[8];
  const float* WO_w = (const float*)d_in[9];
  const float* WO_b = (const float*)d_in[10];

  float* ws   = (float*)d_ws;
  float* QW   = ws + OFF_QW;
  float* QO   = ws + OFF_QO;
  float* Wf   = ws + OFF_WF;
  float* qb   = ws + OFF_QB;
  float* bvo  = ws + OFF_BVO;
  int*   starts = (int*)(ws + OFF_STARTS);
  float* asum = ws + OFF_ASUM;
  float* Q    = ws + OFF_Q;
  float* WQT  = ws + OFF_WQT;
  float* WOT  = ws + OFF_WOT;
  float* Gp   = ws + OFF_GP;

  float* out     = (float*)d_out;                 // [64][64][256]
  float* out_arg = out + 64 * 64 * 256;           // [64][4096]
  float* out_msk = out_arg + 64 * MAXL;           // [64][4096]

  hipMemsetAsync(asum, 0, 64 * 64 * sizeof(float), stream);
  hipMemsetAsync(out_arg, 0, (size_t)2 * 64 * MAXL * sizeof(float), stream);

  k_tr<<<dim3(8, 8, 2), 256, 0, stream>>>(WQ_w, WO_w, WQT, WOT);
  k_wf<<<256, 256, 0, stream>>>(WO_w, WV_w, WV_b, Wf, bvo);
  k_starts<<<1, 128, 0, stream>>>(batch, starts);
  k_q<<<64, 256, 0, stream>>>(Qp, WQT, WQ_b, Q);
  k_fold<<<64, 256, 0, stream>>>(Q, WK_w, WK_b, WOT, QW, QO, qb);

  k_fused<<<dim3(NP, 64), 256, 0, stream>>>(x, starts, QW, qb, Gp, asum,
                                            out_arg, out_msk);
  k_final<<<64 * 4, 256, 0, stream>>>(Gp, NP, Wf, QO, asum, bvo, WO_b, out);
}

// Round 3
// 450.249 us; speedup vs baseline: 3.4120x; 1.6110x over previous
//
#include <hip/hip_runtime.h>

#define N_NODES 131072
#define MAXL 4096
#define NP 8

typedef __attribute__((ext_vector_type(8))) short bf16x8;
typedef __attribute__((ext_vector_type(4))) float f32x4;

// ws float offsets
#define OFF_QW     0u          // 64*256   folded (Q@WK)/16
#define OFF_QO     16384u      // 64*256   Q@WO^T
#define OFF_WF     32768u      // 256*256  WO@WV
#define OFF_QB     98304u      // 64
#define OFF_BVO    98368u      // 256
#define OFF_STARTS 98624u      // 65 ints (padded)
#define OFF_ASUM   98752u      // 64*64
#define OFF_Q      102848u     // 64*256
#define OFF_WQT    119232u     // 256*256
#define OFF_WOT    184768u     // 256*256
#define OFF_GP     250304u     // 8 * 64 * 16384  (end = 8638912 floats = 34.6 MB)

__device__ __forceinline__ unsigned short f2bf(float f) {
  union { float f; unsigned int u; } v; v.f = f;
  unsigned int u = v.u + 0x7FFFu + ((v.u >> 16) & 1u);  // RNE
  return (unsigned short)(u >> 16);
}

// cross-lane sum over kq = lane&7.
// xor1/xor2 via DPP quad_perm (VALU pipe), xor4 via ds_swizzle (LDS pipe).
__device__ __forceinline__ float xor1_add(float v) {
  int r = __builtin_amdgcn_update_dpp(0, __float_as_int(v), 0xB1, 0xF, 0xF, true); // [1,0,3,2]
  return v + __int_as_float(r);
}
__device__ __forceinline__ float xor2_add(float v) {
  int r = __builtin_amdgcn_update_dpp(0, __float_as_int(v), 0x4E, 0xF, 0xF, true); // [2,3,0,1]
  return v + __int_as_float(r);
}
__device__ __forceinline__ float xor4_add(float v) {
  int r = __builtin_amdgcn_ds_swizzle(__float_as_int(v), 0x101F);                  // xor lane^4
  return v + __int_as_float(r);
}
__device__ __forceinline__ float kq_sum(float v) { return xor4_add(xor2_add(xor1_add(v))); }

// ---------------- setup ----------------

// transpose WQ_w (z=0) and WO_w (z=1) into WQT / WOT
__global__ __launch_bounds__(256) void k_tr(const float* __restrict__ WQ_w,
    const float* __restrict__ WO_w, float* __restrict__ WQT, float* __restrict__ WOT)
{
  __shared__ float tile[32][33];
  const float* src = blockIdx.z ? WO_w : WQ_w;
  float* dst = blockIdx.z ? WOT : WQT;
  const int bx = blockIdx.x * 32, by = blockIdx.y * 32;
  const int tx = threadIdx.x & 31, ty = threadIdx.x >> 5;
  #pragma unroll
  for (int i = 0; i < 4; ++i)
    tile[ty + 8 * i][tx] = src[(size_t)(by + ty + 8 * i) * 256 + bx + tx];
  __syncthreads();
  #pragma unroll
  for (int i = 0; i < 4; ++i)
    dst[(size_t)(bx + ty + 8 * i) * 256 + by + tx] = tile[tx][ty + 8 * i];
}

// Q[c][d] = sum_k Qp[c][k] * WQT[k][d] + WQ_b[d]
__global__ __launch_bounds__(256) void k_q(const float* __restrict__ Qp,
    const float* __restrict__ WQT, const float* __restrict__ WQ_b,
    float* __restrict__ Q)
{
  const int c = blockIdx.x, d = threadIdx.x;
  float acc = WQ_b[d];
  for (int k = 0; k < 256; ++k)
    acc += Qp[c * 256 + k] * WQT[k * 256 + d];
  Q[c * 256 + d] = acc;
}

// QW = (Q@WK)/16 (exact, fp64 acc), QO = Q@WO^T, qb = (Q@WK_b)/16
__global__ __launch_bounds__(256) void k_fold(const float* __restrict__ Q,
    const float* __restrict__ WK_w, const float* __restrict__ WK_b,
    const float* __restrict__ WOT,
    float* __restrict__ QW, float* __restrict__ QO, float* __restrict__ qb)
{
  __shared__ float Qrow[256];
  const int c = blockIdx.x, d = threadIdx.x;
  Qrow[d] = Q[c * 256 + d];
  __syncthreads();
  double aqw = 0.0;
  float aqo = 0.f;
  for (int j = 0; j < 256; ++j) {
    float qcj = Qrow[j];
    aqw += (double)qcj * (double)WK_w[j * 256 + d];   // coalesced
    aqo += qcj * WOT[j * 256 + d];                    // coalesced
  }
  QW[c * 256 + d] = (float)(aqw * 0.0625);
  QO[c * 256 + d] = aqo;
  if (d == 0) {
    double s = 0.0;
    for (int j = 0; j < 256; ++j) s += (double)Qrow[j] * (double)WK_b[j];
    qb[c] = (float)(s * 0.0625);
  }
}

__global__ __launch_bounds__(256) void k_wf(const float* __restrict__ WO_w,
    const float* __restrict__ WV_w, const float* __restrict__ WV_b,
    float* __restrict__ Wf, float* __restrict__ bvo)
{
  const int i = blockIdx.x, d = threadIdx.x;
  float acc = 0.f;
  for (int j = 0; j < 256; ++j)
    acc += WO_w[i * 256 + j] * WV_w[j * 256 + d];
  Wf[i * 256 + d] = acc;
  if (d == 0) {
    float s = 0.f;
    for (int j = 0; j < 256; ++j) s += WV_b[j] * WO_w[i * 256 + j];
    bvo[i] = s;
  }
}

__global__ void k_starts(const int* __restrict__ batch, int* __restrict__ starts)
{
  int t = threadIdx.x;
  if (t > 64) return;
  if (t == 0) { starts[0] = 0; return; }
  if (t == 64) { starts[64] = N_NODES; return; }
  int lo = 0, hi = N_NODES;
  while (lo < hi) {
    int mid = (lo + hi) >> 1;
    if (batch[mid] < t) lo = mid + 1; else hi = mid;
  }
  starts[t] = lo;
}

// ---------------- fused: scores + softmax + argmax/mask + G (MFMA) ----------
// grid (NP, 64 graphs), 256 threads, chunk = 32 nodes.
// Score phase: lane = (cp = lane>>3, kq = lane&7). Thread owns clusters
// c0 = 16w+cp, c1 = c0+8. Per (node-oct h, k-half h2) the thread streams its
// 16-k q slice per cluster (8 float4 = 32 transient regs) from global
// (qw = 64 KB, L1/L2-resident). Accumulators: 16. Peak live ~95 arch VGPRs —
// under the 128-arch cap (AGPR split). Rounds 1-2 kept q persistent
// (64 regs) -> ~15 regs over cap -> 1.3-4.3 GB scratch traffic.
// Each b128 xs read feeds 8 FMAs; partial-k sums reduced over kq with DPP
// (xor1/2) + ds_swizzle (xor4). xs columns XOR-swizzled -> conflict-free.

__global__ __launch_bounds__(256, 2) void k_fused(
    const float* __restrict__ x, const int* __restrict__ starts,
    const float* __restrict__ qw, const float* __restrict__ qbv,
    float* __restrict__ Gp, float* __restrict__ asum,
    float* __restrict__ out_arg, float* __restrict__ out_msk)
{
  __shared__ float xs[32][256];                        // fp32 chunk, col-swizzled
  __shared__ float ss[32][68];                         // scores [n][c], 16B-aligned rows
  __shared__ float stats_m[32], stats_i[32];
  __shared__ __align__(16) unsigned short As[64][40];  // a bf16 [c][n]
  __shared__ __align__(16) unsigned short XsT[256][40];// x bf16 transposed [d][n]

  const int t = threadIdx.x;
  const int p = blockIdx.x, b = blockIdx.y;
  const int s0 = starts[b], s1 = starts[b + 1];
  const int w = t >> 6, lane = t & 63;
  const int cp = lane >> 3, kq = lane & 7;
  const int c0 = w * 16 + cp, c1 = c0 + 8;

  const float qb0 = qbv[c0], qb1 = qbv[c1];
  const float* qg0 = qw + (size_t)c0 * 256 + kq * 16;  // thread's q slice bases
  const float* qg1 = qw + (size_t)c1 * 256 + kq * 16;

  f32x4 gacc[16];
  #pragma unroll
  for (int i = 0; i < 16; ++i) gacc[i] = (f32x4){0.f, 0.f, 0.f, 0.f};
  float asv0 = 0.f, asv1 = 0.f;

  const int stcol = (lane * 4) ^ (4 * ((lane >> 3) & 7));  // staging store column
  const int dsz   = t ^ (4 * ((t >> 5) & 7));              // XsT-fill read column

  #pragma unroll 1
  for (int base = s0 + p * 32; base < s1; base += NP * 32) {
    // ---- stage x chunk (coalesced global read, swizzled LDS store)
    #pragma unroll
    for (int i = 0; i < 8; ++i) {
      int r = w * 8 + i;
      int gr = base + r; if (gr >= s1) gr = s1 - 1;
      float4 v = *(const float4*)&x[(size_t)gr * 256 + lane * 4];
      *(float4*)&xs[r][stcol] = v;
    }
    __syncthreads();
    // ---- XsT fill: thread d=t packs its column as bf16 [d][n]
    #pragma unroll
    for (int g = 0; g < 8; ++g) {
      ushort4 pk;
      pk.x = f2bf(xs[g * 4 + 0][dsz]);
      pk.y = f2bf(xs[g * 4 + 1][dsz]);
      pk.z = f2bf(xs[g * 4 + 2][dsz]);
      pk.w = f2bf(xs[g * 4 + 3][dsz]);
      *(ushort4*)&XsT[t][g * 4] = pk;
    }
    // ---- scores: 4 node-octs x 2 k-halves; q streamed 32 regs at a time
    #pragma unroll 1
    for (int h = 0; h < 4; ++h) {
      float a0[8], a1[8];
      #pragma unroll
      for (int n = 0; n < 8; ++n) { a0[n] = 0.f; a1[n] = 0.f; }
      const float* xb = &xs[h * 8][0];
      #pragma unroll 1
      for (int h2 = 0; h2 < 2; ++h2) {
        // load q slice for this k-half: 16 k per cluster (8 float4, transient)
        float4 qA0 = *(const float4*)&qg0[h2 * 128 + 0];
        float4 qA1 = *(const float4*)&qg0[h2 * 128 + 4];
        float4 qA2 = *(const float4*)&qg0[h2 * 128 + 8];
        float4 qA3 = *(const float4*)&qg0[h2 * 128 + 12];
        float4 qB0 = *(const float4*)&qg1[h2 * 128 + 0];
        float4 qB1 = *(const float4*)&qg1[h2 * 128 + 4];
        float4 qB2 = *(const float4*)&qg1[h2 * 128 + 8];
        float4 qB3 = *(const float4*)&qg1[h2 * 128 + 12];
        // 4 k4-groups; swizzled column of orig col h2*128 + kq*16 + k4*4
        #pragma unroll
        for (int k4 = 0; k4 < 4; ++k4) {
          const int colb = h2 * 128 + kq * 16 + k4 * 4;
          const int col = colb ^ (4 * ((colb >> 5) & 7));
          const float4 qa = (k4 == 0) ? qA0 : (k4 == 1) ? qA1 : (k4 == 2) ? qA2 : qA3;
          const float4 qc = (k4 == 0) ? qB0 : (k4 == 1) ? qB1 : (k4 == 2) ? qB2 : qB3;
          #pragma unroll
          for (int n = 0; n < 8; ++n) {
            float4 xv = *(const float4*)&xb[n * 256 + col];
            a0[n] = fmaf(qa.w, xv.w, fmaf(qa.z, xv.z, fmaf(qa.y, xv.y, fmaf(qa.x, xv.x, a0[n]))));
            a1[n] = fmaf(qc.w, xv.w, fmaf(qc.z, xv.z, fmaf(qc.y, xv.y, fmaf(qc.x, xv.x, a1[n]))));
          }
        }
      }
      // reduce partial k-sums over kq; lane kq writes node h*8+kq
      #pragma unroll
      for (int n = 0; n < 8; ++n) {
        float s0v = kq_sum(a0[n]);
        float s1v = kq_sum(a1[n]);
        if (kq == n) {
          ss[h * 8 + n][c0] = s0v + qb0;
          ss[h * 8 + n][c1] = s1v + qb1;
        }
      }
    }
    __syncthreads();
    // ---- softmax stats + argmax: 8 threads/node (oct split + shfl reduce)
    {
      const int nn = t >> 3, oct = t & 7;
      float v8[8];
      #pragma unroll
      for (int u = 0; u < 8; ++u) v8[u] = ss[nn][oct * 8 + u];
      float m = v8[0]; int am = oct * 8;
      #pragma unroll
      for (int u = 1; u < 8; ++u)
        if (v8[u] > m) { m = v8[u]; am = oct * 8 + u; }   // strict >: first max
      #pragma unroll
      for (int d = 1; d < 8; d <<= 1) {
        float mo = __shfl_xor(m, d);
        int ao = __shfl_xor(am, d);
        if (mo > m || (mo == m && ao < am)) { m = mo; am = ao; }
      }
      float s = 0.f;
      #pragma unroll
      for (int u = 0; u < 8; ++u) s += __expf(v8[u] - m);
      #pragma unroll
      for (int d = 1; d < 8; d <<= 1) s += __shfl_xor(s, d);
      if (oct == 0) {
        stats_m[nn] = m;
        stats_i[nn] = 1.f / s;
        int n = base + nn;
        if (n < s1) {
          int pos = n - s0;
          out_arg[(size_t)b * MAXL + pos] = (float)am;
          out_msk[(size_t)b * MAXL + pos] = 1.0f;
        }
      }
    }
    __syncthreads();
    // ---- a-values -> As (bf16) + asum; thread covers n in [4kq, 4kq+4) for c0,c1
    {
      unsigned short pb0[4], pb1[4];
      #pragma unroll
      for (int i = 0; i < 4; ++i) {
        int nn = 4 * kq + i;
        bool valid = (base + nn) < s1;
        float m = stats_m[nn], inv = stats_i[nn];
        float av0 = valid ? __expf(ss[nn][c0] - m) * inv : 0.f;
        float av1 = valid ? __expf(ss[nn][c1] - m) * inv : 0.f;
        asv0 += av0; asv1 += av1;
        pb0[i] = f2bf(av0);
        pb1[i] = f2bf(av1);
      }
      *(ushort4*)&As[c0][4 * kq] = *(const ushort4*)pb0;
      *(ushort4*)&As[c1][4 * kq] = *(const ushort4*)pb1;
    }
    __syncthreads();
    // ---- G MFMA: wave w owns clusters 16w..16w+16
    {
      const int q = lane >> 4, mm = lane & 15;
      bf16x8 afrag = *(const bf16x8*)&As[16 * w + mm][q * 8];
      #pragma unroll
      for (int dt = 0; dt < 16; ++dt) {
        bf16x8 bfrag = *(const bf16x8*)&XsT[16 * dt + mm][q * 8];
        gacc[dt] = __builtin_amdgcn_mfma_f32_16x16x32_bf16(afrag, bfrag, gacc[dt], 0, 0, 0);
      }
    }
    __syncthreads();
  }

  // ---- epilogue: store G slab (D layout: row=4*(lane>>4)+r, col=lane&15)
  {
    float* g = Gp + ((size_t)p * 64 + b) * 16384;
    const int q = lane >> 4, mm = lane & 15;
    #pragma unroll
    for (int dt = 0; dt < 16; ++dt)
      #pragma unroll
      for (int r = 0; r < 4; ++r)
        g[(size_t)(16 * w + q * 4 + r) * 256 + 16 * dt + mm] = gacc[dt][r];
  }
  // asum: reduce per-thread partials over kq, one atomic per cluster
  asv0 = kq_sum(asv0);
  asv1 = kq_sum(asv1);
  if (kq == 0) {
    atomicAdd(&asum[b * 64 + c0], asv0);
    atomicAdd(&asum[b * 64 + c1], asv1);
  }
}

// ---------------- finalize: out = relu(qo + (sum_p Gp)@Wf^T + asum*bvo + b) --

__global__ __launch_bounds__(256) void k_final(const float* __restrict__ Gp,
    int npart, const float* __restrict__ Wf, const float* __restrict__ qo,
    const float* __restrict__ asum, const float* __restrict__ bvo,
    const float* __restrict__ WO_b, float* __restrict__ out)
{
  __shared__ float gs[64 * 68];
  __shared__ float wfs[64 * 68];
  const int t = threadIdx.x;
  const int b = blockIdx.x >> 2;
  const int is = (blockIdx.x & 3) * 64;
  const int tx = t & 15, ty = t >> 4;
  const int sr = t >> 4, sq = t & 15;

  float acc[4][4];
  #pragma unroll
  for (int j = 0; j < 4; ++j)
    #pragma unroll
    for (int u = 0; u < 4; ++u) acc[j][u] = 0.f;

  for (int kc = 0; kc < 4; ++kc) {
    const int k0 = kc * 64;
    #pragma unroll
    for (int u = 0; u < 4; ++u) {
      int row = sr + 16 * u;
      float4 g = make_float4(0.f, 0.f, 0.f, 0.f);
      for (int p = 0; p < npart; ++p) {
        float4 gv = *(const float4*)&Gp[((size_t)p * 64 + b) * 16384
                                        + row * 256 + k0 + sq * 4];
        g.x += gv.x; g.y += gv.y; g.z += gv.z; g.w += gv.w;
      }
      *(float4*)&gs[row * 68 + sq * 4] = g;
      *(float4*)&wfs[row * 68 + sq * 4] =
          *(const float4*)&Wf[(size_t)(is + row) * 256 + k0 + sq * 4];
    }
    __syncthreads();
    #pragma unroll
    for (int k4 = 0; k4 < 16; ++k4) {
      float4 gr[4], wr[4];
      #pragma unroll
      for (int j = 0; j < 4; ++j) gr[j] = *(const float4*)&gs[(ty + 16 * j) * 68 + k4 * 4];
      #pragma unroll
      for (int u = 0; u < 4; ++u) wr[u] = *(const float4*)&wfs[(tx + 16 * u) * 68 + k4 * 4];
      #pragma unroll
      for (int j = 0; j < 4; ++j)
        #pragma unroll
        for (int u = 0; u < 4; ++u)
          acc[j][u] += gr[j].x * wr[u].x + gr[j].y * wr[u].y
                     + gr[j].z * wr[u].z + gr[j].w * wr[u].w;
    }
    __syncthreads();
  }

  #pragma unroll
  for (int j = 0; j < 4; ++j)
    #pragma unroll
    for (int u = 0; u < 4; ++u) {
      int cc = ty + 16 * j, i = is + tx + 16 * u;
      float v = acc[j][u] + qo[cc * 256 + i] + asum[b * 64 + cc] * bvo[i] + WO_b[i];
      out[(size_t)b * 16384 + cc * 256 + i] = fmaxf(v, 0.f);
    }
}

// ---------------- launch ----------------

extern "C" void kernel_launch(void* const* d_in, const int* in_sizes, int n_in,
                              void* d_out, int out_size, void* d_ws, size_t ws_size,
                              hipStream_t stream) {
  const float* x    = (const float*)d_in[0];
  const int*   batch= (const int*)d_in[1];
  const float* Qp   = (const float*)d_in[2];
  const float* WQ_w = (const float*)d_in[3];
  const float* WQ_b = (const float*)d_in[4];
  const float* WK_w = (const float*)d_in[5];
  const float* WK_b = (const float*)d_in[6];
  const float* WV_w = (const float*)d_in[7];
  const float* WV_b = (const float*)d_in[8];
  const float* WO_w = (const float*)d_in[9];
  const float* WO_b = (const float*)d_in[10];

  float* ws   = (float*)d_ws;
  float* QW   = ws + OFF_QW;
  float* QO   = ws + OFF_QO;
  float* Wf   = ws + OFF_WF;
  float* qb   = ws + OFF_QB;
  float* bvo  = ws + OFF_BVO;
  int*   starts = (int*)(ws + OFF_STARTS);
  float* asum = ws + OFF_ASUM;
  float* Q    = ws + OFF_Q;
  float* WQT  = ws + OFF_WQT;
  float* WOT  = ws + OFF_WOT;
  float* Gp   = ws + OFF_GP;

  float* out     = (float*)d_out;                 // [64][64][256]
  float* out_arg = out + 64 * 64 * 256;           // [64][4096]
  float* out_msk = out_arg + 64 * MAXL;           // [64][4096]

  hipMemsetAsync(asum, 0, 64 * 64 * sizeof(float), stream);
  hipMemsetAsync(out_arg, 0, (size_t)2 * 64 * MAXL * sizeof(float), stream);

  k_tr<<<dim3(8, 8, 2), 256, 0, stream>>>(WQ_w, WO_w, WQT, WOT);
  k_wf<<<256, 256, 0, stream>>>(WO_w, WV_w, WV_b, Wf, bvo);
  k_starts<<<1, 128, 0, stream>>>(batch, starts);
  k_q<<<64, 256, 0, stream>>>(Qp, WQT, WQ_b, Q);
  k_fold<<<64, 256, 0, stream>>>(Q, WK_w, WK_b, WOT, QW, QO, qb);

  k_fused<<<dim3(NP, 64), 256, 0, stream>>>(x, starts, QW, qb, Gp, asum,
                                            out_arg, out_msk);
  k_final<<<64 * 4, 256, 0, stream>>>(Gp, NP, Wf, QO, asum, bvo, WO_b, out);
}